// Round 8
// baseline (138.908 us; speedup 1.0000x reference)
//
#include <hip/hip_runtime.h>
#include <hip/hip_bf16.h>

#define Bsz 4
#define Lsz 2048
#define Hsz 8

typedef __attribute__((ext_vector_type(8)))  short bf16x8;
typedef __attribute__((ext_vector_type(4)))  short bf16x4;
typedef __attribute__((ext_vector_type(4)))  float f32x4;

__device__ __forceinline__ short f2bs(float f) {   // RNE (same converter prep_kv used)
    union { float f; unsigned u; } v; v.f = f;
    unsigned r = v.u + 0x7FFFu + ((v.u >> 16) & 1u);
    return (short)(r >> 16);
}
__device__ __forceinline__ short f2bs_rh(float f) { // round-half-up, 2 ops (P pack)
    return (short)((__float_as_uint(f) + 0x8000u) >> 16);
}

// ---------------- single fused kernel: NO prep pass, NO workspace ----------------
// R0-R6 lesson: per-iteration GPU time = ws-poison fill (~43us, 256MiB) + prep_kv
// (~40us, never in top-5) + main (~41-48us). Fusing the fp32->bf16 conversion into
// the main loop deletes prep outright and leaves d_ws untouched.
// R7 lesson: the cvtpk-inline-asm + union fragment build NaN'd; R8 rebuilds the
// same structure with the PROVEN scalar f2bs converters (bit-identical numerics to
// the passing R6: prep converted the same fp32 values with the same f2bs).
//
// 256 thr = 4 waves; wave kq owns keys kq*16..+16 of every tile x ALL 64 queries.
// Per tile, per wave: K slice = 4x float4 fp32 loads (rows kq*16+ln, 32B-aligned),
// V slice = 16 scalar dword loads (rows kq*16+quad*4+j, col dg*16+ln), converted
// in-register with f2bs. No LDS K/V staging, no loop barriers, no waitcnt asm -
// per-wave independent loops; compiler manages all waits. Q frags in LDS
// (R4-proven; keeps VGPR under the (256,3)~170 cap - R5 showed Q-in-regs spills
// at 128). K/V fp32 re-reads are mostly L2-resident (64 KB K-tile read by ~32
// co-phased blocks on the same XCD).
// LDS: dls 8K + Qs 8K + Ored 32K (epilogue only) = 48 KB -> 3 blocks/CU (= VGPR
// limit at (256,3)), 12 waves/CU.
__global__ __launch_bounds__(256, 3) void dsattn_fused(
    const float* __restrict__ q,
    const float* __restrict__ ksrc,
    const float* __restrict__ vsrc,
    const float* __restrict__ tau,
    const float* __restrict__ delta,
    float* __restrict__ out)
{
    __shared__ float dls[Lsz];                       //  8 KB c2*delta[b][:]
    __shared__ __align__(16) short Qs[4096];         //  8 KB Q frags
    __shared__ __align__(16) float Ored[2][4096];    // 32 KB epilogue overlay

    const int tid  = threadIdx.x;
    const int kq   = tid >> 6;        // wave id == key-quarter
    const int lane = tid & 63;
    const int ln   = lane & 15;
    const int quad = lane >> 4;

    const int bh = blockIdx.x;
    const int b  = bh >> 3, h = bh & 7;
    // spread qt chains so long/short blocks mix across CUs (66 tiles per y-group)
    const int y = blockIdx.y, g8 = y >> 3, a = y & 7;
    const int qt = (g8 == 0) ? 31 - 2*a : (g8 == 1) ? 2*a
                 : (g8 == 2) ? 30 - 2*a : 2*a + 1;
    const int q0 = qt * 64;
    const int T  = qt + 1;            // 64-key tiles

    const float c2  = 0.125f * 1.44269504f;   // scale * log2(e)
    const float st2 = c2 * tau[b];

    // stage c2*delta (256 thr x 8 floats) - prologue only
    {
        const float* dsrc = delta + (size_t)b*Lsz + tid*8;
        float4 av = *(const float4*)(dsrc);
        float4 cv = *(const float4*)(dsrc + 4);
        av.x*=c2; av.y*=c2; av.z*=c2; av.w*=c2;
        cv.x*=c2; cv.y*=c2; cv.z*=c2; cv.w*=c2;
        *(float4*)&dls[tid*8]     = av;
        *(float4*)&dls[tid*8 + 4] = cv;
    }

    // Q frags -> LDS (wave kq builds q-group qg=kq; B-operand of 16x16x32)
    {
        const float* qrow = q + (((size_t)b*Lsz + q0 + kq*16 + ln)*Hsz + h)*64;
        float4 a0 = *(const float4*)(qrow + quad*8);
        float4 a1 = *(const float4*)(qrow + quad*8 + 4);
        float4 b0 = *(const float4*)(qrow + 32 + quad*8);
        float4 b1 = *(const float4*)(qrow + 32 + quad*8 + 4);
        bf16x8 q0f = {f2bs(a0.x),f2bs(a0.y),f2bs(a0.z),f2bs(a0.w),
                      f2bs(a1.x),f2bs(a1.y),f2bs(a1.z),f2bs(a1.w)};
        bf16x8 q1f = {f2bs(b0.x),f2bs(b0.y),f2bs(b0.z),f2bs(b0.w),
                      f2bs(b1.x),f2bs(b1.y),f2bs(b1.z),f2bs(b1.w)};
        *(bf16x8*)(&Qs[(kq*2+0)*512 + lane*8]) = q0f;
        *(bf16x8*)(&Qs[(kq*2+1)*512 + lane*8]) = q1f;
    }

    // per-wave fp32 source pointers; tile stride = 64 rows = 32768 floats
    // K lane: row kq*16+ln, cols [quad*8,+8) and [32+quad*8,+8)
    const float* kp = ksrc + (((size_t)b*Lsz + kq*16 + ln)*Hsz + h)*64 + quad*8;
    // V lane: rows kq*16+quad*4+j (j=0..3, +j*512), col dg*16+ln (+dg*16)
    const float* vp = vsrc + (((size_t)b*Lsz + kq*16 + quad*4)*Hsz + h)*64 + ln;

    f32x4 oacc[4][4];                 // [dg][qg]; O[q=qg*16+ln][d=dg*16+quad*4+i]
    #pragma unroll
    for (int dg = 0; dg < 4; ++dg)
        #pragma unroll
        for (int qg = 0; qg < 4; ++qg)
            oacc[dg][qg] = (f32x4){0.f,0.f,0.f,0.f};
    float l_acc[4] = {0.f,0.f,0.f,0.f};

    __syncthreads();                  // Qs + dls ready (only pre-epilogue barrier)

#define TILE_BODY(t_, MASKED) do {                                          \
        /* K loads first (first consumer), then V (consumed after softmax) */\
        const float4 ka0_ = *(const float4*)(kp);                           \
        const float4 ka1_ = *(const float4*)(kp + 4);                       \
        const float4 kb0_ = *(const float4*)(kp + 32);                      \
        const float4 kb1_ = *(const float4*)(kp + 36);                      \
        float vs_[16];                                                      \
        _Pragma("unroll")                                                   \
        for (int dg = 0; dg < 4; ++dg)                                      \
            _Pragma("unroll")                                               \
            for (int j = 0; j < 4; ++j)                                     \
                vs_[dg*4+j] = vp[j*512 + dg*16];                            \
        /* K -> bf16 A-operand frags, scalar f2bs (== prep_kv's values) */  \
        bf16x8 kf0_ = {f2bs(ka0_.x),f2bs(ka0_.y),f2bs(ka0_.z),f2bs(ka0_.w),\
                       f2bs(ka1_.x),f2bs(ka1_.y),f2bs(ka1_.z),f2bs(ka1_.w)};\
        bf16x8 kf1_ = {f2bs(kb0_.x),f2bs(kb0_.y),f2bs(kb0_.z),f2bs(kb0_.w),\
                       f2bs(kb1_.x),f2bs(kb1_.y),f2bs(kb1_.z),f2bs(kb1_.w)};\
        f32x4 sacc_[4];                                                     \
        __builtin_amdgcn_s_setprio(1);                                      \
        _Pragma("unroll")                                                   \
        for (int qg = 0; qg < 4; ++qg) {                                    \
            bf16x8 qa_ = *(const bf16x8*)(&Qs[(qg*2+0)*512 + lane*8]);      \
            bf16x8 qb_ = *(const bf16x8*)(&Qs[(qg*2+1)*512 + lane*8]);      \
            f32x4 z_ = (f32x4){0.f,0.f,0.f,0.f};                            \
            z_ = __builtin_amdgcn_mfma_f32_16x16x32_bf16(kf0_, qa_, z_, 0,0,0); \
            sacc_[qg] = __builtin_amdgcn_mfma_f32_16x16x32_bf16(kf1_, qb_, z_, 0,0,0); \
        }                                                                   \
        __builtin_amdgcn_s_setprio(0);                                      \
        if (MASKED) {                                                       \
            _Pragma("unroll")                                               \
            for (int qg = 0; qg < 4; ++qg)                                  \
                _Pragma("unroll")                                           \
                for (int r = 0; r < 4; ++r)                                 \
                    if (kq*16 + quad*4 + r > qg*16 + ln) sacc_[qg][r] = -1e30f; \
        }                                                                   \
        f32x4 dlv_ = *(const f32x4*)&dls[(t_)*64 + kq*16 + quad*4];         \
        bf16x4 pT_[4];                                                      \
        _Pragma("unroll")                                                   \
        for (int qg = 0; qg < 4; ++qg) {                                    \
            float p0_ = __builtin_amdgcn_exp2f(fmaf(sacc_[qg][0], st2, dlv_[0])); \
            float p1_ = __builtin_amdgcn_exp2f(fmaf(sacc_[qg][1], st2, dlv_[1])); \
            float p2_ = __builtin_amdgcn_exp2f(fmaf(sacc_[qg][2], st2, dlv_[2])); \
            float p3_ = __builtin_amdgcn_exp2f(fmaf(sacc_[qg][3], st2, dlv_[3])); \
            l_acc[qg] += (p0_ + p1_) + (p2_ + p3_);                         \
            pT_[qg] = (bf16x4){f2bs_rh(p0_), f2bs_rh(p1_),                  \
                               f2bs_rh(p2_), f2bs_rh(p3_)};                 \
        }                                                                   \
        /* V -> bf16 A-operand frags, scalar f2bs */                        \
        bf16x4 vf_[4];                                                      \
        _Pragma("unroll")                                                   \
        for (int dg = 0; dg < 4; ++dg)                                      \
            vf_[dg] = (bf16x4){f2bs(vs_[dg*4+0]), f2bs(vs_[dg*4+1]),        \
                               f2bs(vs_[dg*4+2]), f2bs(vs_[dg*4+3])};       \
        __builtin_amdgcn_s_setprio(1);                                      \
        _Pragma("unroll")                                                   \
        for (int dg = 0; dg < 4; ++dg)                                      \
            _Pragma("unroll")                                               \
            for (int qg = 0; qg < 4; ++qg)                                  \
                oacc[dg][qg] = __builtin_amdgcn_mfma_f32_16x16x16bf16_1k(   \
                    vf_[dg], pT_[qg], oacc[dg][qg], 0,0,0);                 \
        __builtin_amdgcn_s_setprio(0);                                      \
        kp += 32768; vp += 32768;                                           \
    } while (0)

    for (int t = 0; t < T - 1; ++t) TILE_BODY(t, false);
    TILE_BODY(T - 1, true);           // diagonal (masked) tile

    // ---- epilogue: 4-way cross-kq reduction of O and l via LDS overlays ----
    float lq[4];
    #pragma unroll
    for (int qg = 0; qg < 4; ++qg) {
        float s = l_acc[qg];
        s += __shfl_xor(s, 16, 64);
        s += __shfl_xor(s, 32, 64);
        lq[qg] = s;                   // full-wave l for (qg, q=ln), replicated
    }
    float* KbF = &Ored[0][0];         // 16 KB wave-1 O, layout (dg*4+qg)*256+lane*4
    float* VbF = &Ored[1][0];         // 16 KB wave-3 O
    float* lred = dls;                // 256 f: [kq][qg][16 q]
    __syncthreads();                  // all loop reads of Qs/dls done

    if (lane < 16)
        #pragma unroll
        for (int qg = 0; qg < 4; ++qg) lred[kq*64 + qg*16 + ln] = lq[qg];
    if (kq == 1 || kq == 3) {
        float* dst = (kq == 1) ? KbF : VbF;
        #pragma unroll
        for (int dg = 0; dg < 4; ++dg)
            #pragma unroll
            for (int qg = 0; qg < 4; ++qg)
                *(f32x4*)(dst + (dg*4+qg)*256 + lane*4) = oacc[dg][qg];
    }
    __syncthreads();
    if (kq == 0 || kq == 2) {
        const float* srcp = (kq == 0) ? KbF : VbF;
        #pragma unroll
        for (int dg = 0; dg < 4; ++dg)
            #pragma unroll
            for (int qg = 0; qg < 4; ++qg) {
                f32x4 v = *(const f32x4*)(srcp + (dg*4+qg)*256 + lane*4);
                oacc[dg][qg][0] += v[0]; oacc[dg][qg][1] += v[1];
                oacc[dg][qg][2] += v[2]; oacc[dg][qg][3] += v[3];
            }
    }
    __syncthreads();
    if (kq == 2) {
        #pragma unroll
        for (int dg = 0; dg < 4; ++dg)
            #pragma unroll
            for (int qg = 0; qg < 4; ++qg)
                *(f32x4*)(KbF + (dg*4+qg)*256 + lane*4) = oacc[dg][qg];
    }
    __syncthreads();
    if (kq == 0) {
        float inv[4];
        #pragma unroll
        for (int qg = 0; qg < 4; ++qg)
            inv[qg] = 1.0f / (lred[qg*16 + ln] + lred[64 + qg*16 + ln]
                            + lred[128 + qg*16 + ln] + lred[192 + qg*16 + ln]);
        #pragma unroll
        for (int qg = 0; qg < 4; ++qg) {
            float* orow = out + (((size_t)b*Lsz + q0 + qg*16 + ln)*Hsz + h)*64;
            #pragma unroll
            for (int dg = 0; dg < 4; ++dg) {
                f32x4 v = *(const f32x4*)(KbF + (dg*4+qg)*256 + lane*4);
                float4 o = {(oacc[dg][qg][0] + v[0]) * inv[qg],
                            (oacc[dg][qg][1] + v[1]) * inv[qg],
                            (oacc[dg][qg][2] + v[2]) * inv[qg],
                            (oacc[dg][qg][3] + v[3]) * inv[qg]};
                *(float4*)(orow + dg*16 + quad*4) = o;
            }
        }
    }
#undef TILE_BODY
}

extern "C" void kernel_launch(void* const* d_in, const int* in_sizes, int n_in,
                              void* d_out, int out_size, void* d_ws, size_t ws_size,
                              hipStream_t stream) {
    (void)in_sizes; (void)n_in; (void)out_size; (void)d_ws; (void)ws_size;
    const float* q     = (const float*)d_in[0];
    const float* k     = (const float*)d_in[1];
    const float* v     = (const float*)d_in[2];
    const float* tau   = (const float*)d_in[3];
    const float* delta = (const float*)d_in[4];
    float* out = (float*)d_out;

    // single fused kernel: no prep pass, workspace untouched
    dsattn_fused<<<dim3(Bsz*Hsz, 32), dim3(256), 0, stream>>>(q, k, v, tau, delta, out);
}